// Round 1
// baseline (514.821 us; speedup 1.0000x reference)
//
#include <hip/hip_runtime.h>
#include <cmath>

#define NN 8192

typedef _Float16 half8 __attribute__((ext_vector_type(8)));
typedef float floatx4 __attribute__((ext_vector_type(4)));

// ---------------------------------------------------------------------------
// h_kernel: H[ch] = X @ w_ch  (X: [8192,32] f32, w: [32,32] f32), output fp16
// stored directly in MFMA B-fragment order:
//   Hfrag[ch][t][tile][lane][elem], t = j>>5, lane = (n&15)|(((j&31)>>3)<<4),
//   tile = n>>4, elem = j&7   -> agg kernel B-load is one dwordx4 per lane.
// ---------------------------------------------------------------------------
__global__ __launch_bounds__(256) void h_kernel(
    const float* __restrict__ X,
    const float* __restrict__ w1, const float* __restrict__ w2,
    const float* __restrict__ w3, _Float16* __restrict__ Hfrag) {
  __shared__ float wl[3][32][32];
  const int tid = threadIdx.x;
  const float* ws3[3] = {w1, w2, w3};
  for (int i = tid; i < 3 * 32 * 32; i += 256)
    ((float*)wl)[i] = ws3[i >> 10][i & 1023];   // wl[ch][d][n] = w_ch[d*32+n]
  __syncthreads();
  const int n = tid & 31, jb = tid >> 5;        // thread = (out dim, j-block of 8)
  const int j0 = blockIdx.x * 64 + jb * 8;
  const int t = j0 >> 5;
  const int lane = (n & 15) | (((j0 & 31) >> 3) << 4);
  const int tile = n >> 4;
  for (int ch = 0; ch < 3; ++ch) {
    half8 hv;
#pragma unroll
    for (int jj = 0; jj < 8; ++jj) {
      const float4* xr = (const float4*)(X + (size_t)(j0 + jj) * 32);
      float acc = 0.f;
#pragma unroll
      for (int d4 = 0; d4 < 8; ++d4) {
        float4 x = xr[d4];
        acc += x.x * wl[ch][d4 * 4 + 0][n];
        acc += x.y * wl[ch][d4 * 4 + 1][n];
        acc += x.z * wl[ch][d4 * 4 + 2][n];
        acc += x.w * wl[ch][d4 * 4 + 3][n];
      }
      hv[jj] = (_Float16)acc;
    }
    size_t idx = ((((size_t)ch * 256 + t) * 2 + tile) * 64 + lane) * 8;
    *(half8*)(Hfrag + idx) = hv;
  }
}

// ---------------------------------------------------------------------------
// agg_kernel: o = sum_k (adj==k) @ H_k  via fp16 MFMA, masks built on the fly.
// MODE 0: layer 1 — raw adj in, Z1=relu(o+b) out, optional 2-bit packed adj out
// MODE 1: layer 2 — packed adj in, relu(o+b) row-sum-pooled into partials
// MODE 2: layer 2 fallback — raw adj in, pooled out
// Grid 512 wgs x 256 thr: wg owns 16 rows; 4 waves split j into quarters.
// ---------------------------------------------------------------------------
template <int MODE>
__global__ __launch_bounds__(256) void agg_kernel(
    const int* __restrict__ adj, const unsigned char* __restrict__ packed_in,
    unsigned short* __restrict__ packed_out, const half8* __restrict__ Hf,
    const float* __restrict__ bias, float* __restrict__ Z1,
    float* __restrict__ partials) {
  const int tid = threadIdx.x;
  const int w = tid >> 6, lane = tid & 63;
  const int m = lane & 15, q = lane >> 4;     // A-row within tile, k-quad
  const int rbase = blockIdx.x * 16;
  const int row = rbase + m;
  const int jh = w;                           // j quarter (2048 j each)
  floatx4 acc0 = {0.f, 0.f, 0.f, 0.f}, acc1 = {0.f, 0.f, 0.f, 0.f};

  const size_t arow = (size_t)row * NN;
  int4 v0, v1;
  unsigned int pv = 0;
  if (MODE != 1) {
    const int4* ap = (const int4*)(adj + arow + jh * 2048 + q * 8);
    v0 = ap[0]; v1 = ap[1];
  } else {
    pv = *(const unsigned short*)(packed_in + (size_t)row * 2048 +
                                  ((jh * 2048 + q * 8) >> 2));
  }
  for (int tl = 0; tl < 64; ++tl) {
    const int t = jh * 64 + tl;
    // prefetch next iteration's adjacency (keeps ~2KB/wave in flight)
    int4 nx0, nx1; unsigned int npv = 0;
    const int tn = (tl < 63) ? tl + 1 : tl;
    if (MODE != 1) {
      const int4* ap = (const int4*)(adj + arow + jh * 2048 + tn * 32 + q * 8);
      nx0 = ap[0]; nx1 = ap[1];
    } else {
      npv = *(const unsigned short*)(packed_in + (size_t)row * 2048 +
                                     ((jh * 2048 + tn * 32 + q * 8) >> 2));
    }
    // B fragments (pre-laid-out, fully coalesced 16B/lane, L2/L3-resident)
    const size_t hb = (size_t)t * 128 + lane;
    half8 b00 = Hf[hb],          b01 = Hf[hb + 64];
    half8 b10 = Hf[hb + 32768],  b11 = Hf[hb + 32768 + 64];
    half8 b20 = Hf[hb + 65536],  b21 = Hf[hb + 65536 + 64];
    // build 0/1 fp16 masks in A-fragment layout
    half8 a1, a2, a3;
    if (MODE == 1) {
#pragma unroll
      for (int i = 0; i < 8; ++i) {
        const int av = (pv >> (2 * i)) & 3;
        a1[i] = (av == 1) ? (_Float16)1.f : (_Float16)0.f;
        a2[i] = (av == 2) ? (_Float16)1.f : (_Float16)0.f;
        a3[i] = (av == 3) ? (_Float16)1.f : (_Float16)0.f;
      }
    } else {
      const int av[8] = {v0.x, v0.y, v0.z, v0.w, v1.x, v1.y, v1.z, v1.w};
      unsigned int pk = 0;
#pragma unroll
      for (int i = 0; i < 8; ++i) {
        a1[i] = (av[i] == 1) ? (_Float16)1.f : (_Float16)0.f;
        a2[i] = (av[i] == 2) ? (_Float16)1.f : (_Float16)0.f;
        a3[i] = (av[i] == 3) ? (_Float16)1.f : (_Float16)0.f;
        if (MODE == 0) pk |= ((unsigned int)av[i]) << (2 * i);
      }
      if (MODE == 0 && packed_out)
        *(unsigned short*)((unsigned char*)packed_out + (size_t)row * 2048 +
                           ((jh * 2048 + tl * 32 + q * 8) >> 2)) =
            (unsigned short)pk;
    }
    acc0 = __builtin_amdgcn_mfma_f32_16x16x32_f16(a1, b00, acc0, 0, 0, 0);
    acc0 = __builtin_amdgcn_mfma_f32_16x16x32_f16(a2, b10, acc0, 0, 0, 0);
    acc0 = __builtin_amdgcn_mfma_f32_16x16x32_f16(a3, b20, acc0, 0, 0, 0);
    acc1 = __builtin_amdgcn_mfma_f32_16x16x32_f16(a1, b01, acc1, 0, 0, 0);
    acc1 = __builtin_amdgcn_mfma_f32_16x16x32_f16(a2, b11, acc1, 0, 0, 0);
    acc1 = __builtin_amdgcn_mfma_f32_16x16x32_f16(a3, b21, acc1, 0, 0, 0);
    v0 = nx0; v1 = nx1; pv = npv;
  }
  // combine the 4 j-quarters through LDS
  __shared__ float red[4][2][64][4];
#pragma unroll
  for (int r = 0; r < 4; ++r) {
    red[w][0][lane][r] = acc0[r];
    red[w][1][lane][r] = acc1[r];
  }
  __syncthreads();
  __shared__ float pool[32][4];
  if (w == 0) {
    float c0[4], c1[4];
#pragma unroll
    for (int r = 0; r < 4; ++r) {
      c0[r] = red[0][0][lane][r] + red[1][0][lane][r] +
              red[2][0][lane][r] + red[3][0][lane][r];
      c1[r] = red[0][1][lane][r] + red[1][1][lane][r] +
              red[2][1][lane][r] + red[3][1][lane][r];
    }
    // C/D layout (16x16, verified): col = lane&15, row = (lane>>4)*4 + reg
    const float b0 = bias[m], b1 = bias[16 + m];
    if (MODE == 0) {
#pragma unroll
      for (int r = 0; r < 4; ++r) {
        const int ro = rbase + q * 4 + r;
        float u0 = c0[r] + b0; u0 = u0 > 0.f ? u0 : 0.f;
        float u1 = c1[r] + b1; u1 = u1 > 0.f ? u1 : 0.f;
        Z1[(size_t)ro * 32 + m] = u0;
        Z1[(size_t)ro * 32 + 16 + m] = u1;
      }
    } else {
      float s0 = 0.f, s1 = 0.f;
#pragma unroll
      for (int r = 0; r < 4; ++r) {
        const float u0 = c0[r] + b0; s0 += u0 > 0.f ? u0 : 0.f;
        const float u1 = c1[r] + b1; s1 += u1 > 0.f ? u1 : 0.f;
      }
      pool[m][q] = s0;
      pool[16 + m][q] = s1;
    }
  }
  if (MODE != 0) {
    __syncthreads();
    if (tid < 32)
      partials[(size_t)blockIdx.x * 32 + tid] =
          pool[tid][0] + pool[tid][1] + pool[tid][2] + pool[tid][3];
  }
}

// ---------------------------------------------------------------------------
// fc_kernel: reduce pooled partials, fc0+relu, fc1, sigmoid -> out[0]
// ---------------------------------------------------------------------------
__global__ __launch_bounds__(64) void fc_kernel(
    const float* __restrict__ partials, const float* __restrict__ W0,
    const float* __restrict__ b0, const float* __restrict__ W1,
    const float* __restrict__ b1, float* __restrict__ out) {
  __shared__ float z[32], y[32];
  const int t = threadIdx.x;
  if (t < 32) {
    float s = 0.f;
    for (int wg = 0; wg < 512; ++wg) s += partials[wg * 32 + t];
    z[t] = s;
  }
  __syncthreads();
  if (t < 32) {
    float acc = b0[t];
    for (int n = 0; n < 32; ++n) acc += W0[t * 32 + n] * z[n];
    y[t] = acc > 0.f ? acc : 0.f;
  }
  __syncthreads();
  if (t == 0) {
    float acc = b1[0];
    for (int mm = 0; mm < 32; ++mm) acc += W1[mm] * y[mm];
    out[0] = 1.f / (1.f + expf(-acc));
  }
}

extern "C" void kernel_launch(void* const* d_in, const int* in_sizes, int n_in,
                              void* d_out, int out_size, void* d_ws,
                              size_t ws_size, hipStream_t stream) {
  const float* V   = (const float*)d_in[0];
  const int*   adj = (const int*)d_in[1];
  const float *w10 = (const float*)d_in[2], *w20 = (const float*)d_in[3],
              *w30 = (const float*)d_in[4], *gb0 = (const float*)d_in[5];
  const float *w11 = (const float*)d_in[6], *w21 = (const float*)d_in[7],
              *w31 = (const float*)d_in[8], *gb1 = (const float*)d_in[9];
  const float *fW0 = (const float*)d_in[10], *fb0 = (const float*)d_in[11],
              *fW1 = (const float*)d_in[12], *fb1 = (const float*)d_in[13];
  float* out = (float*)d_out;
  char* ws = (char*)d_ws;

  _Float16*       Hfrag    = (_Float16*)ws;                    // 1,572,864 B
  float*          Z1       = (float*)(ws + 1572864);           // 1,048,576 B
  float*          partials = (float*)(ws + 2621440);           //    65,536 B
  unsigned short* packed   = (unsigned short*)(ws + 2686976);  // 16,777,216 B
  const bool pack = ws_size >= (size_t)2686976 + 16777216;

  h_kernel<<<128, 256, 0, stream>>>(V, w10, w20, w30, Hfrag);
  if (pack)
    agg_kernel<0><<<512, 256, 0, stream>>>(adj, nullptr, packed,
                                           (const half8*)Hfrag, gb0, Z1, nullptr);
  else
    agg_kernel<0><<<512, 256, 0, stream>>>(adj, nullptr, nullptr,
                                           (const half8*)Hfrag, gb0, Z1, nullptr);
  h_kernel<<<128, 256, 0, stream>>>(Z1, w11, w21, w31, Hfrag);
  if (pack)
    agg_kernel<1><<<512, 256, 0, stream>>>(nullptr, (const unsigned char*)packed,
                                           nullptr, (const half8*)Hfrag, gb1,
                                           nullptr, partials);
  else
    agg_kernel<2><<<512, 256, 0, stream>>>(adj, nullptr, nullptr,
                                           (const half8*)Hfrag, gb1,
                                           nullptr, partials);
  fc_kernel<<<1, 64, 0, stream>>>(partials, fW0, fb0, fW1, fb1, out);
}

// Round 2
// 496.265 us; speedup vs baseline: 1.0374x; 1.0374x over previous
//
#include <hip/hip_runtime.h>
#include <cmath>

#define NN 8192

typedef _Float16 half8 __attribute__((ext_vector_type(8)));
typedef float floatx4 __attribute__((ext_vector_type(4)));

// ---------------------------------------------------------------------------
// h_kernel<L2>: H[ch] = X @ w_ch, output fp16 in MFMA B-fragment order:
//   Hfrag[ch][t][tile][lane][elem], t=j>>5, lane=(n&15)|(((j&31)>>3)<<4),
//   tile=n>>4, elem=j&7.
// L2=0: X = V (f32 [8192,32]).  L2=1: X = relu(sum_c Zpart[c] + gbias).
// Grid dim3(128,3): blockIdx.y = channel, block owns 64 rows of X.
// ---------------------------------------------------------------------------
template <int L2>
__global__ __launch_bounds__(256) void h_kernel(
    const float* __restrict__ X, const float* __restrict__ w1,
    const float* __restrict__ w2, const float* __restrict__ w3,
    const float* __restrict__ gbias, _Float16* __restrict__ Hfrag) {
  __shared__ float wl[32][32];   // wl[d][n]
  __shared__ float Xs[64][32];
  const int tid = threadIdx.x;
  const int ch = blockIdx.y;
  const float* wsrc = (ch == 0) ? w1 : (ch == 1) ? w2 : w3;
  for (int i = tid; i < 1024; i += 256) ((float*)wl)[i] = wsrc[i];
  const size_t base = (size_t)blockIdx.x * 2048 + tid * 8;
  if (L2 == 0) {
    float4 x0 = ((const float4*)(X + base))[0];
    float4 x1 = ((const float4*)(X + base))[1];
    *((float4*)(&Xs[0][0] + tid * 8)) = x0;
    *((float4*)(&Xs[0][0] + tid * 8 + 4)) = x1;
  } else {
    float4 s0 = {0.f, 0.f, 0.f, 0.f}, s1 = {0.f, 0.f, 0.f, 0.f};
#pragma unroll
    for (int c = 0; c < 4; ++c) {
      const float4* p = (const float4*)(X + (size_t)c * NN * 32 + base);
      float4 a = p[0], b = p[1];
      s0.x += a.x; s0.y += a.y; s0.z += a.z; s0.w += a.w;
      s1.x += b.x; s1.y += b.y; s1.z += b.z; s1.w += b.w;
    }
    const int c0 = (tid * 8) & 31;
    const float4 b0 = *(const float4*)(gbias + c0);
    const float4 b1 = *(const float4*)(gbias + c0 + 4);
    s0.x += b0.x; s0.y += b0.y; s0.z += b0.z; s0.w += b0.w;
    s1.x += b1.x; s1.y += b1.y; s1.z += b1.z; s1.w += b1.w;
    s0.x = s0.x > 0.f ? s0.x : 0.f; s0.y = s0.y > 0.f ? s0.y : 0.f;
    s0.z = s0.z > 0.f ? s0.z : 0.f; s0.w = s0.w > 0.f ? s0.w : 0.f;
    s1.x = s1.x > 0.f ? s1.x : 0.f; s1.y = s1.y > 0.f ? s1.y : 0.f;
    s1.z = s1.z > 0.f ? s1.z : 0.f; s1.w = s1.w > 0.f ? s1.w : 0.f;
    *((float4*)(&Xs[0][0] + tid * 8)) = s0;
    *((float4*)(&Xs[0][0] + tid * 8 + 4)) = s1;
  }
  __syncthreads();
  const int n = tid & 31, jb = tid >> 5;
  const int j0 = blockIdx.x * 64 + jb * 8;
  const int t = j0 >> 5;
  const int lane = (n & 15) | (((j0 & 31) >> 3) << 4);
  const int tile = n >> 4;
  half8 hv;
#pragma unroll
  for (int jj = 0; jj < 8; ++jj) {
    const float4* xr = (const float4*)(&Xs[jb * 8 + jj][0]);
    float acc = 0.f;
#pragma unroll
    for (int d4 = 0; d4 < 8; ++d4) {
      float4 x = xr[d4];
      acc += x.x * wl[d4 * 4 + 0][n];
      acc += x.y * wl[d4 * 4 + 1][n];
      acc += x.z * wl[d4 * 4 + 2][n];
      acc += x.w * wl[d4 * 4 + 3][n];
    }
    hv[jj] = (_Float16)acc;
  }
  size_t idx = ((((size_t)ch * 256 + t) * 2 + tile) * 64 + lane) * 8;
  *(half8*)(Hfrag + idx) = hv;
}

// ---------------------------------------------------------------------------
// agg_kernel: o = sum_k (adj==k) @ H_k via fp16 MFMA, masks built on the fly.
// Grid 2048 x 256: block = (row-group of 16) x (j-chunk of 2048); 4 waves
// split the chunk into 512-j slices -> 8192 waves = 100% occupancy.
// All modes write raw partial sums (no bias/relu) to Zpart[c][row][32].
// MODE 0: raw adj in + 2-bit packed adj out. MODE 1: packed adj in.
// MODE 2: raw adj in, no packed out.
// ---------------------------------------------------------------------------
template <int MODE>
__global__ __launch_bounds__(256, 8) void agg_kernel(
    const int* __restrict__ adj, const unsigned char* __restrict__ packed_in,
    unsigned short* __restrict__ packed_out, const half8* __restrict__ Hf,
    float* __restrict__ Zpart) {
  const int tid = threadIdx.x;
  const int w = tid >> 6, lane = tid & 63;
  const int m = lane & 15, q = lane >> 4;   // A-row within tile, k-quad
  const int rg = blockIdx.x >> 2, c = blockIdx.x & 3;
  const int rbase = rg * 16;
  const int row = rbase + m;
  const int jbase = c * 2048 + w * 512;     // this wave's 512-j slice
  floatx4 acc0 = {0.f, 0.f, 0.f, 0.f}, acc1 = {0.f, 0.f, 0.f, 0.f};

  const size_t arow = (size_t)row * NN;
  int4 v0, v1;
  unsigned int pv = 0;
  if (MODE != 1) {
    const int4* ap = (const int4*)(adj + arow + jbase + q * 8);
    v0 = ap[0]; v1 = ap[1];
  } else {
    pv = *(const unsigned short*)(packed_in + (size_t)row * 2048 +
                                  ((jbase + q * 8) >> 2));
  }
  for (int tl = 0; tl < 16; ++tl) {
    const int t = c * 64 + w * 16 + tl;     // global k-tile index
    int4 nx0, nx1; unsigned int npv = 0;
    const int tn = (tl < 15) ? tl + 1 : tl;
    if (MODE != 1) {
      const int4* ap = (const int4*)(adj + arow + jbase + tn * 32 + q * 8);
      nx0 = ap[0]; nx1 = ap[1];
    } else {
      npv = *(const unsigned short*)(packed_in + (size_t)row * 2048 +
                                     ((jbase + tn * 32 + q * 8) >> 2));
    }
    const size_t hb = (size_t)t * 128 + lane;
    half8 b00 = Hf[hb],          b01 = Hf[hb + 64];
    half8 b10 = Hf[hb + 32768],  b11 = Hf[hb + 32768 + 64];
    half8 b20 = Hf[hb + 65536],  b21 = Hf[hb + 65536 + 64];
    half8 a1, a2, a3;
    if (MODE == 1) {
#pragma unroll
      for (int i = 0; i < 8; ++i) {
        const int av = (pv >> (2 * i)) & 3;
        a1[i] = (av == 1) ? (_Float16)1.f : (_Float16)0.f;
        a2[i] = (av == 2) ? (_Float16)1.f : (_Float16)0.f;
        a3[i] = (av == 3) ? (_Float16)1.f : (_Float16)0.f;
      }
    } else {
      const int av[8] = {v0.x, v0.y, v0.z, v0.w, v1.x, v1.y, v1.z, v1.w};
      unsigned int pk = 0;
#pragma unroll
      for (int i = 0; i < 8; ++i) {
        a1[i] = (av[i] == 1) ? (_Float16)1.f : (_Float16)0.f;
        a2[i] = (av[i] == 2) ? (_Float16)1.f : (_Float16)0.f;
        a3[i] = (av[i] == 3) ? (_Float16)1.f : (_Float16)0.f;
        if (MODE == 0) pk |= ((unsigned int)av[i]) << (2 * i);
      }
      if (MODE == 0 && packed_out)
        *(unsigned short*)((unsigned char*)packed_out + (size_t)row * 2048 +
                           ((jbase + tl * 32 + q * 8) >> 2)) =
            (unsigned short)pk;
    }
    acc0 = __builtin_amdgcn_mfma_f32_16x16x32_f16(a1, b00, acc0, 0, 0, 0);
    acc0 = __builtin_amdgcn_mfma_f32_16x16x32_f16(a2, b10, acc0, 0, 0, 0);
    acc0 = __builtin_amdgcn_mfma_f32_16x16x32_f16(a3, b20, acc0, 0, 0, 0);
    acc1 = __builtin_amdgcn_mfma_f32_16x16x32_f16(a1, b01, acc1, 0, 0, 0);
    acc1 = __builtin_amdgcn_mfma_f32_16x16x32_f16(a2, b11, acc1, 0, 0, 0);
    acc1 = __builtin_amdgcn_mfma_f32_16x16x32_f16(a3, b21, acc1, 0, 0, 0);
    v0 = nx0; v1 = nx1; pv = npv;
  }
  __shared__ float red[4][2][64][4];
#pragma unroll
  for (int r = 0; r < 4; ++r) {
    red[w][0][lane][r] = acc0[r];
    red[w][1][lane][r] = acc1[r];
  }
  __syncthreads();
  if (w == 0) {
    // C/D layout (16x16): col = lane&15, row = (lane>>4)*4 + reg
#pragma unroll
    for (int r = 0; r < 4; ++r) {
      const float c0 = red[0][0][lane][r] + red[1][0][lane][r] +
                       red[2][0][lane][r] + red[3][0][lane][r];
      const float c1 = red[0][1][lane][r] + red[1][1][lane][r] +
                       red[2][1][lane][r] + red[3][1][lane][r];
      const int ro = rbase + q * 4 + r;
      float* zp = Zpart + ((size_t)c * NN + ro) * 32;
      zp[m] = c0;
      zp[16 + m] = c1;
    }
  }
}

// ---------------------------------------------------------------------------
// pool_kernel: pooled[col] partials = sum_rows relu(sum_c Zpart[c] + bias)
// Grid 32 x 256: block owns 256 rows.
// ---------------------------------------------------------------------------
__global__ __launch_bounds__(256) void pool_kernel(
    const float* __restrict__ Zpart, const float* __restrict__ bias,
    float* __restrict__ partials) {
  const int tid = threadIdx.x;
  const int col = tid & 31, ro = tid >> 5;
  const float b = bias[col];
  float s = 0.f;
  for (int rr = 0; rr < 32; ++rr) {
    const size_t r = (size_t)blockIdx.x * 256 + ro * 32 + rr;
    float v = Zpart[r * 32 + col] + Zpart[(size_t)NN * 32 + r * 32 + col] +
              Zpart[(size_t)2 * NN * 32 + r * 32 + col] +
              Zpart[(size_t)3 * NN * 32 + r * 32 + col] + b;
    s += v > 0.f ? v : 0.f;
  }
  __shared__ float red[8][32];
  red[ro][col] = s;
  __syncthreads();
  if (tid < 32) {
    float t = 0.f;
#pragma unroll
    for (int i = 0; i < 8; ++i) t += red[i][tid];
    partials[(size_t)blockIdx.x * 32 + tid] = t;
  }
}

// ---------------------------------------------------------------------------
// fc_kernel: reduce pooled partials (np x 32), fc0+relu, fc1, sigmoid
// ---------------------------------------------------------------------------
__global__ __launch_bounds__(256) void fc_kernel(
    const float* __restrict__ partials, int np, const float* __restrict__ W0,
    const float* __restrict__ b0, const float* __restrict__ W1,
    const float* __restrict__ b1, float* __restrict__ out) {
  __shared__ float acc8[8][32];
  __shared__ float z[32], y[32];
  const int tid = threadIdx.x;
  const int col = tid & 31, ch = tid >> 5;
  float s = 0.f;
  for (int i = ch; i < np; i += 8) s += partials[(size_t)i * 32 + col];
  acc8[ch][col] = s;
  __syncthreads();
  if (tid < 32) {
    float t = 0.f;
#pragma unroll
    for (int i = 0; i < 8; ++i) t += acc8[i][tid];
    z[tid] = t;
  }
  __syncthreads();
  if (tid < 32) {
    float acc = b0[tid];
    for (int n = 0; n < 32; ++n) acc += W0[tid * 32 + n] * z[n];
    y[tid] = acc > 0.f ? acc : 0.f;
  }
  __syncthreads();
  if (tid == 0) {
    float acc = b1[0];
    for (int mm = 0; mm < 32; ++mm) acc += W1[mm] * y[mm];
    out[0] = 1.f / (1.f + expf(-acc));
  }
}

extern "C" void kernel_launch(void* const* d_in, const int* in_sizes, int n_in,
                              void* d_out, int out_size, void* d_ws,
                              size_t ws_size, hipStream_t stream) {
  const float* V   = (const float*)d_in[0];
  const int*   adj = (const int*)d_in[1];
  const float *w10 = (const float*)d_in[2], *w20 = (const float*)d_in[3],
              *w30 = (const float*)d_in[4], *gb0 = (const float*)d_in[5];
  const float *w11 = (const float*)d_in[6], *w21 = (const float*)d_in[7],
              *w31 = (const float*)d_in[8], *gb1 = (const float*)d_in[9];
  const float *fW0 = (const float*)d_in[10], *fb0 = (const float*)d_in[11],
              *fW1 = (const float*)d_in[12], *fb1 = (const float*)d_in[13];
  float* out = (float*)d_out;
  char* ws = (char*)d_ws;

  _Float16*       Hfrag    = (_Float16*)ws;                    // 1,572,864 B
  float*          Zpart    = (float*)(ws + 1572864);           // 4,194,304 B
  float*          partials = (float*)(ws + 5767168);           //   262,144 B
  unsigned short* packed   = (unsigned short*)(ws + 6029312);  // 16,777,216 B
  const bool pack = ws_size >= (size_t)6029312 + 16777216;

  h_kernel<0><<<dim3(128, 3), 256, 0, stream>>>(V, w10, w20, w30, nullptr,
                                                Hfrag);
  agg_kernel<0><<<2048, 256, 0, stream>>>(adj, nullptr,
                                          pack ? packed : nullptr,
                                          (const half8*)Hfrag, Zpart);
  h_kernel<1><<<dim3(128, 3), 256, 0, stream>>>(Zpart, w11, w21, w31, gb0,
                                                Hfrag);
  if (pack)
    agg_kernel<1><<<2048, 256, 0, stream>>>(nullptr,
                                            (const unsigned char*)packed,
                                            nullptr, (const half8*)Hfrag,
                                            Zpart);
  else
    agg_kernel<2><<<2048, 256, 0, stream>>>(adj, nullptr, nullptr,
                                            (const half8*)Hfrag, Zpart);
  pool_kernel<<<32, 256, 0, stream>>>(Zpart, gb1, partials);
  fc_kernel<<<1, 256, 0, stream>>>(partials, 32, fW0, fb0, fW1, fb1, out);
}